// Round 5
// baseline (112.229 us; speedup 1.0000x reference)
//
#include <hip/hip_runtime.h>
#include <hip/hip_bf16.h>

// Problem constants (match reference)
#define BB 4
#define CC 32
#define HH 64
#define WW 64
#define KK 64
#define PIX (HH * WW)      // 4096
#define NBC (BB * CC)      // 128 planes

// ---------------------------------------------------------------------------
// Numerics: reference's max-subtraction is pure stability; u~N(0,1), rf<=1
// bounds exp args by ~6 -> no overflow in f32. Verified absmax 0 vs ref with:
//   inv_k = 1 / (1 + sum_{rf>0} exp(u*rf))
//   h[p]  = sum_k [rf_k>0] exp(u*rf_k) * inv_k ; out = 2x2 block max of h.
//
// Lesson from R4: data-dependent loop bounds (bbox) destroyed memory-level
// parallelism (no unroll -> serialized L2 latency) and added a graph node.
// This version is DENSE with fixed trip counts everywhere, but fused into a
// single kernel: phase1 results (inv_k) live in LDS, never round-trip
// through global, and one launch node replaces two.
//
// Grid 256 = (bc, half). Each block redundantly computes all 64 inv_k
// (2x redundant phase1; ~1.7 us chip-wide) so phase2 needs no cross-block
// communication; phase2 covers the block's 16 row-pairs from LDS.
// ---------------------------------------------------------------------------

__global__ __launch_bounds__(512) void rf_fused(
        const float* __restrict__ u,
        const float* __restrict__ rfs,
        float* __restrict__ out) {
    const int bc   = blockIdx.x >> 1;
    const int half = blockIdx.x & 1;
    const int t    = threadIdx.x;
    const int w    = t >> 6;     // wave 0..7
    const int l    = t & 63;     // lane

    __shared__ float su[PIX];    // u plane, 16 KB
    __shared__ float sinv[KK];

    // Stage u plane: 1024 float4, 512 threads x 2
    {
        const float4* ug = (const float4*)(u + (size_t)bc * PIX);
        float4* s4 = (float4*)su;
        s4[t]       = ug[t];
        s4[t + 512] = ug[t + 512];
    }
    __syncthreads();

    const float4* su4 = (const float4*)su;

    // -------- Phase 1: wave w computes k = 8w..8w+7; inv into LDS --------
    for (int kk = 0; kk < 8; ++kk) {
        const int k = w * 8 + kk;
        const float4* r4 = (const float4*)(rfs + (size_t)k * PIX);
        float s = 0.f;
        #pragma unroll
        for (int i = 0; i < 16; ++i) {          // fixed trip, 16 loads in flight
            const float4 rv = r4[i * 64 + l];
            const float4 uv = su4[i * 64 + l];
            s += (rv.x > 0.f) ? __expf(uv.x * rv.x) : 0.f;
            s += (rv.y > 0.f) ? __expf(uv.y * rv.y) : 0.f;
            s += (rv.z > 0.f) ? __expf(uv.z * rv.z) : 0.f;
            s += (rv.w > 0.f) ? __expf(uv.w * rv.w) : 0.f;
        }
        #pragma unroll
        for (int off = 32; off > 0; off >>= 1)
            s += __shfl_xor(s, off, 64);
        if (l == 0) sinv[k] = 1.f / (1.f + s);
    }
    __syncthreads();

    // -------- Phase 2: 16 row-pairs for this half, 2 per wave --------
    #pragma unroll
    for (int j = 0; j < 2; ++j) {
        const int rp = half * 16 + w * 2 + j;   // row pair 0..31
        const int r0 = rp * 2;
        const float u0 = su[r0 * WW + l];
        const float u1 = su[r0 * WW + WW + l];
        const float* rfp = rfs + r0 * WW + l;

        float h0 = 0.f, h1 = 0.f;
        #pragma unroll 8
        for (int k = 0; k < KK; ++k) {          // fixed trip, unroll-8 batches
            const float rv0 = rfp[(size_t)k * PIX];
            const float rv1 = rfp[(size_t)k * PIX + WW];
            const float fi  = sinv[k];
            h0 += (rv0 > 0.f) ? __expf(u0 * rv0) * fi : 0.f;
            h1 += (rv1 > 0.f) ? __expf(u1 * rv1) * fi : 0.f;
        }

        // 2x2 pool: vertical in-register, horizontal across lane pairs
        const float v = fmaxf(h0, h1);
        const float o = fmaxf(v, __shfl_xor(v, 1, 64));
        if ((l & 1) == 0)
            out[(size_t)bc * (HH / 2) * (WW / 2) + rp * 32 + (l >> 1)] = o;
    }
}

extern "C" void kernel_launch(void* const* d_in, const int* in_sizes, int n_in,
                              void* d_out, int out_size, void* d_ws, size_t ws_size,
                              hipStream_t stream) {
    const float* u   = (const float*)d_in[0];
    const float* rfs = (const float*)d_in[1];
    float* out       = (float*)d_out;
    rf_fused<<<NBC * 2, 512, 0, stream>>>(u, rfs, out);
}

// Round 6
// 78.351 us; speedup vs baseline: 1.4324x; 1.4324x over previous
//
#include <hip/hip_runtime.h>
#include <hip/hip_bf16.h>

// Problem constants (match reference)
#define BB 4
#define CC 32
#define HH 64
#define WW 64
#define KK 64
#define PIX (HH * WW)      // 4096
#define NBC (BB * CC)      // 128 planes
#define NPAIR (NBC / 2)    // 64 bc-pairs

// ---------------------------------------------------------------------------
// Numerics: reference's max-subtraction is pure stability; u~N(0,1), rf<=1
// bounds exp args by ~6 -> no overflow in f32 (verified absmax 0 in R3-R5):
//   inv_k = 1 / (1 + sum_{rf>0} exp(u*rf))
//   h[p]  = sum_k [rf_k>0] exp(u*rf_k) * inv_k ; out = 2x2 block max of h.
//
// Structure lessons (R4: dynamic bounds kill MLP; R5: 256-block fusion kills
// occupancy): keep R3's two-kernel, many-wave, fixed-trip-unrolled shape,
// and raise arithmetic intensity by amortizing every rf load over a PAIR of
// bc planes (rf L2 traffic halves; 2x exp work per load in flight).
// ---------------------------------------------------------------------------

// Phase 1: grid = NPAIR*16 = 1024 blocks x 256 thr. Block = (pair, kgroup).
// Wave w computes k = kg*4+w for BOTH planes of the pair; u planes in LDS.
__global__ __launch_bounds__(256) void rf_phase1(
        const float* __restrict__ u,
        const float* __restrict__ rfs,
        float* __restrict__ inv) {
    const int pair = blockIdx.x >> 4;
    const int kg   = blockIdx.x & 15;
    const int t = threadIdx.x, w = t >> 6, l = t & 63;
    const int bc0 = pair * 2, bc1 = bc0 + 1;

    __shared__ float su0[PIX], su1[PIX];   // 2 u planes, 32 KB
    {
        const float4* g0 = (const float4*)(u + (size_t)bc0 * PIX);
        const float4* g1 = (const float4*)(u + (size_t)bc1 * PIX);
        float4* s0 = (float4*)su0; float4* s1 = (float4*)su1;
        #pragma unroll
        for (int i = 0; i < 4; ++i) {
            s0[t + 256 * i] = g0[t + 256 * i];
            s1[t + 256 * i] = g1[t + 256 * i];
        }
    }
    __syncthreads();

    const int k = kg * 4 + w;
    const float4* r4  = (const float4*)(rfs + (size_t)k * PIX);
    const float4* s04 = (const float4*)su0;
    const float4* s14 = (const float4*)su1;

    float a0 = 0.f, a1 = 0.f;
    #pragma unroll
    for (int i = 0; i < 16; ++i) {         // fixed trip: 16 rf loads in flight
        const float4 rv = r4[i * 64 + l];
        const float4 u0 = s04[i * 64 + l];
        const float4 u1 = s14[i * 64 + l];
        a0 += (rv.x > 0.f) ? __expf(u0.x * rv.x) : 0.f;
        a0 += (rv.y > 0.f) ? __expf(u0.y * rv.y) : 0.f;
        a0 += (rv.z > 0.f) ? __expf(u0.z * rv.z) : 0.f;
        a0 += (rv.w > 0.f) ? __expf(u0.w * rv.w) : 0.f;
        a1 += (rv.x > 0.f) ? __expf(u1.x * rv.x) : 0.f;
        a1 += (rv.y > 0.f) ? __expf(u1.y * rv.y) : 0.f;
        a1 += (rv.z > 0.f) ? __expf(u1.z * rv.z) : 0.f;
        a1 += (rv.w > 0.f) ? __expf(u1.w * rv.w) : 0.f;
    }
    #pragma unroll
    for (int off = 32; off > 0; off >>= 1) {   // two independent reductions
        a0 += __shfl_xor(a0, off, 64);
        a1 += __shfl_xor(a1, off, 64);
    }
    if (l == 0) {
        inv[bc0 * KK + k] = 1.f / (1.f + a0);
        inv[bc1 * KK + k] = 1.f / (1.f + a1);
    }
}

// Phase 2: grid = NPAIR*8 = 512 blocks x 256 thr. Block = (pair, rp-group).
// Wave w owns row-pair rp = rpg*4+w for BOTH planes: rf row loaded once,
// applied to 2 planes (4 accumulators). inv pairs broadcast from LDS.
__global__ __launch_bounds__(256) void rf_phase2(
        const float* __restrict__ u,
        const float* __restrict__ rfs,
        const float* __restrict__ inv,
        float* __restrict__ out) {
    const int pair = blockIdx.x >> 3;
    const int rpg  = blockIdx.x & 7;
    const int t = threadIdx.x, w = t >> 6, l = t & 63;
    const int bc0 = pair * 2, bc1 = bc0 + 1;
    const int rp = rpg * 4 + w;            // row pair 0..31 (wave-uniform)
    const int r0 = rp * 2;

    __shared__ float2 sinv[KK];
    if (t < KK) sinv[t] = make_float2(inv[bc0 * KK + t], inv[bc1 * KK + t]);

    const float u00 = u[(size_t)bc0 * PIX + r0 * WW + l];
    const float u01 = u[(size_t)bc0 * PIX + r0 * WW + WW + l];
    const float u10 = u[(size_t)bc1 * PIX + r0 * WW + l];
    const float u11 = u[(size_t)bc1 * PIX + r0 * WW + WW + l];
    __syncthreads();

    const float* rfp = rfs + r0 * WW + l;
    float h00 = 0.f, h01 = 0.f, h10 = 0.f, h11 = 0.f;
    #pragma unroll 8
    for (int k = 0; k < KK; ++k) {         // fixed trip, unroll-8 batches
        const float rv0 = rfp[(size_t)k * PIX];
        const float rv1 = rfp[(size_t)k * PIX + WW];
        const float2 fi = sinv[k];
        h00 += (rv0 > 0.f) ? __expf(u00 * rv0) * fi.x : 0.f;
        h01 += (rv1 > 0.f) ? __expf(u01 * rv1) * fi.x : 0.f;
        h10 += (rv0 > 0.f) ? __expf(u10 * rv0) * fi.y : 0.f;
        h11 += (rv1 > 0.f) ? __expf(u11 * rv1) * fi.y : 0.f;
    }

    // 2x2 pool: vertical in-register, horizontal across lane pairs
    const float v0 = fmaxf(h00, h01);
    const float v1 = fmaxf(h10, h11);
    const float o0 = fmaxf(v0, __shfl_xor(v0, 1, 64));
    const float o1 = fmaxf(v1, __shfl_xor(v1, 1, 64));
    if ((l & 1) == 0) {
        out[(size_t)bc0 * (HH / 2) * (WW / 2) + rp * 32 + (l >> 1)] = o0;
        out[(size_t)bc1 * (HH / 2) * (WW / 2) + rp * 32 + (l >> 1)] = o1;
    }
}

extern "C" void kernel_launch(void* const* d_in, const int* in_sizes, int n_in,
                              void* d_out, int out_size, void* d_ws, size_t ws_size,
                              hipStream_t stream) {
    const float* u   = (const float*)d_in[0];
    const float* rfs = (const float*)d_in[1];
    float* out       = (float*)d_out;
    float* inv       = (float*)d_ws;       // 128*64 floats = 32 KB scratch

    rf_phase1<<<NPAIR * 16, 256, 0, stream>>>(u, rfs, inv);
    rf_phase2<<<NPAIR * 8, 256, 0, stream>>>(u, rfs, inv, out);
}